// Round 4
// baseline (166.080 us; speedup 1.0000x reference)
//
#include <hip/hip_runtime.h>
#include <hip/hip_bf16.h>

typedef __attribute__((ext_vector_type(8))) short bf16x8;
typedef __attribute__((ext_vector_type(16))) float f32x16;

static __device__ __forceinline__ uint bf16rne(float f) {
    uint u = __float_as_uint(f);
    return (u + 0x7fffu + ((u >> 16) & 1u)) >> 16;
}

// K1: style_plus1[b][c] = 1 + affine_b[c] + dot(w[b,:], affine_w[c,:])
__global__ void k_style(const float* __restrict__ w, const float* __restrict__ aw,
                        const float* __restrict__ ab, float* __restrict__ style) {
    int idx = blockIdx.x * 4 + (threadIdx.x >> 6);
    int lane = threadIdx.x & 63;
    int b = idx >> 9, c = idx & 511;
    const float* wp = w + b * 512;
    const float* ap = aw + (size_t)c * 512;
    float s = 0.f;
    #pragma unroll
    for (int i = 0; i < 8; ++i) s += wp[lane + i * 64] * ap[lane + i * 64];
    #pragma unroll
    for (int m = 32; m; m >>= 1) s += __shfl_xor(s, m, 64);
    if (lane == 0) style[idx] = s + ab[c] + 1.0f;
}

// K2: Wf = bf16 weights in 32x32x16 MFMA A-fragment order.
// idx = grp*294912 + chunk*18432 + tap*2048 + fm*1024 + ks*512 + lane*8 + e
// where o = grp*64 + fm*32 + (lane&31), c = chunk*32 + ks*16 + (lane>>5)*8 + e
__global__ void k_wprep(const float* __restrict__ weight, ushort* __restrict__ Wf,
                        float* __restrict__ wsq) {
    int t = blockIdx.x * 256 + threadIdx.x;          // (o,c)
    int o = t >> 9, c = t & 511;
    int grp = o >> 6, fm = (o >> 5) & 1, mrow = o & 31;
    int chunk = c >> 5, ks = (c >> 4) & 1, khi = (c >> 3) & 1, e = c & 7;
    int lane = khi * 32 + mrow;
    size_t base = (size_t)grp * 294912 + (size_t)chunk * 18432
                + (size_t)fm * 1024 + (size_t)ks * 512 + (size_t)lane * 8 + e;
    const float* wp = weight + (size_t)t * 9;
    float sq = 0.f;
    #pragma unroll
    for (int j = 0; j < 9; ++j) {
        float v = wp[j];
        sq += v * v;
        Wf[base + (size_t)j * 2048] = (ushort)bf16rne(v);
    }
    wsq[t] = sq;
}

// K3: sigma[b][o] = rsqrt( sum_c style^2[b,c] * wsq[o,c] + eps )
__global__ void k_sigma(const float* __restrict__ style, const float* __restrict__ wsq,
                        float* __restrict__ sigma) {
    int idx = blockIdx.x * 4 + (threadIdx.x >> 6);
    int lane = threadIdx.x & 63;
    int b = idx >> 9, o = idx & 511;
    const float* sp = style + b * 512;
    const float* qp = wsq + (size_t)o * 512;
    float s = 0.f;
    #pragma unroll
    for (int i = 0; i < 8; ++i) {
        float st = sp[lane + i * 64];
        s += st * st * qp[lane + i * 64];
    }
    #pragma unroll
    for (int m = 32; m; m >>= 1) s += __shfl_xor(s, m, 64);
    if (lane == 0) sigma[idx] = rsqrtf(s + 1e-8f);
}

// load A tap-row DY of chunk CC into slot array SL (12 uint4: dx*4+fm*2+ks)
#define ALOAD(SL, DY, CC) { \
    const ushort* p_ = Wgrp + (size_t)(CC) * 18432 + (DY) * 6144; \
    _Pragma("unroll") for (int q_ = 0; q_ < 12; ++q_) \
        SL[q_] = *(const uint4*)(p_ + q_ * 512); }

// B fragment: input row R, tap dx DX, 32-col group CG, k-half KS
#define BRD(R, DX, CG, KS) \
    (*(const bf16x8*)&sX[cur][((R) * 66 + (CG) * 32 + l31 + (DX)) * 40 + (KS) * 16 + hi * 8])

// MFMA group: A-slot S against bv[], output row H
#define HG(S, H) \
    _Pragma("unroll") for (int dx_ = 0; dx_ < 3; ++dx_) \
    _Pragma("unroll") for (int ks_ = 0; ks_ < 2; ++ks_) \
    _Pragma("unroll") for (int fm_ = 0; fm_ < 2; ++fm_) \
    _Pragma("unroll") for (int cg_ = 0; cg_ < 2; ++cg_) \
        acc[fm_][(H) * 2 + cg_] = __builtin_amdgcn_mfma_f32_32x32x16_bf16( \
            *(const bf16x8*)&S[dx_ * 4 + fm_ * 2 + ks_], bv[dx_ * 4 + cg_ * 2 + ks_], \
            acc[fm_][(H) * 2 + cg_], 0, 0, 0);

#define PHASE(R, BODY) { \
    bf16x8 bv[12]; \
    _Pragma("unroll") for (int dx_ = 0; dx_ < 3; ++dx_) \
    _Pragma("unroll") for (int cg_ = 0; cg_ < 2; ++cg_) \
    _Pragma("unroll") for (int ks_ = 0; ks_ < 2; ++ks_) \
        bv[dx_ * 4 + cg_ * 2 + ks_] = BRD(R, dx_, cg_, ks_); \
    BODY }

// K4: implicit-GEMM conv, 32x32x16 MFMA. Block: 256 o x 128 px (2 rows),
// 4 waves of 64o x 128px each. x modulated+packed during staging. 1 wave/SIMD.
__global__ __launch_bounds__(256, 1) void k_conv(
    const float* __restrict__ x, const ushort* __restrict__ Wf,
    const float* __restrict__ style, const float* __restrict__ sigma,
    const float* __restrict__ bias, float* __restrict__ out) {

    __shared__ ushort sX[2][4 * 66 * 40];   // [buf][row][col][40ch-padded], 42 KB

    const int tid = threadIdx.x, bid = blockIdx.x;
    const int pb = bid & 255, ob1 = bid >> 8;     // o-half-major: L2 locality per round
    const int b = pb >> 5, y0 = (pb & 31) * 2;
    const int wv = tid >> 6, lane = tid & 63;
    const int l31 = lane & 31, hi = lane >> 5;

    // staging role: wave wv stages input row wv (wave-uniform y)
    const int scol = tid & 63;
    const int yy = y0 - 1 + wv;
    const bool yok = (unsigned)yy < 64u;
    const int colpos = scol + 1;
    const float* xcb = x + (((size_t)(b * 512) * 64 + yy) * 64 + scol);
    const float* stb = style + b * 512;

    const ushort* Wgrp = Wf + (size_t)(ob1 * 4 + wv) * 294912 + lane * 8;

    f32x16 acc[2][4];
    #pragma unroll
    for (int i = 0; i < 2; ++i)
        #pragma unroll
        for (int j = 0; j < 4; ++j)
            acc[i][j] = (f32x16){0,0,0,0,0,0,0,0,0,0,0,0,0,0,0,0};

    // zero halo pads (colpos 0 and 65, both buffers) once
    if (tid < 64) {
        int buf = tid >> 5, r = (tid >> 3) & 3, side = (tid >> 2) & 1, g = tid & 3;
        *(uint4*)&sX[buf][(r * 66 + side * 65) * 40 + g * 8] = make_uint4(0u, 0u, 0u, 0u);
    }

    // prologue: stage chunk 0 into buf 0
    {
        float xv[32];
        if (yok) {
            #pragma unroll
            for (int j = 0; j < 32; ++j) xv[j] = xcb[(size_t)j * 4096] * stb[j];
        } else {
            #pragma unroll
            for (int j = 0; j < 32; ++j) xv[j] = 0.f;
        }
        ushort* dst = &sX[0][(wv * 66 + colpos) * 40];
        #pragma unroll
        for (int g = 0; g < 4; ++g) {
            uint4 pk;
            pk.x = bf16rne(xv[g*8+0]) | (bf16rne(xv[g*8+1]) << 16);
            pk.y = bf16rne(xv[g*8+2]) | (bf16rne(xv[g*8+3]) << 16);
            pk.z = bf16rne(xv[g*8+4]) | (bf16rne(xv[g*8+5]) << 16);
            pk.w = bf16rne(xv[g*8+6]) | (bf16rne(xv[g*8+7]) << 16);
            *(uint4*)&dst[g * 8] = pk;
        }
    }
    uint4 a0[12], a1[12], a2[12];
    ALOAD(a0, 0, 0) ALOAD(a1, 1, 0) ALOAD(a2, 2, 0)
    __syncthreads();

    int cur = 0;
    #pragma unroll 1
    for (int cci = 0; cci < 16; ++cci) {
        const int ncc = (cci + 1) & 15;      // wrap: harmless in-bounds reload

        // T14: issue next chunk's x loads early (hide under MFMA phases)
        float xv[32];
        if (yok) {
            #pragma unroll
            for (int j = 0; j < 32; ++j)
                xv[j] = xcb[(size_t)(ncc * 32 + j) * 4096] * stb[ncc * 32 + j];
        } else {
            #pragma unroll
            for (int j = 0; j < 32; ++j) xv[j] = 0.f;
        }

        PHASE(0, HG(a0, 0))
        PHASE(1, HG(a1, 0) HG(a0, 1))
        PHASE(2, HG(a2, 0) HG(a1, 1))
        ALOAD(a0, 0, ncc)                    // slot0 dead after phase 1
        PHASE(3, HG(a2, 1))
        ALOAD(a1, 1, ncc)                    // slot1 dead after phase 2

        // pack + commit next chunk's x tile to other buffer
        {
            ushort* dst = &sX[cur ^ 1][(wv * 66 + colpos) * 40];
            #pragma unroll
            for (int g = 0; g < 4; ++g) {
                uint4 pk;
                pk.x = bf16rne(xv[g*8+0]) | (bf16rne(xv[g*8+1]) << 16);
                pk.y = bf16rne(xv[g*8+2]) | (bf16rne(xv[g*8+3]) << 16);
                pk.z = bf16rne(xv[g*8+4]) | (bf16rne(xv[g*8+5]) << 16);
                pk.w = bf16rne(xv[g*8+6]) | (bf16rne(xv[g*8+7]) << 16);
                *(uint4*)&dst[g * 8] = pk;
            }
        }
        __syncthreads();
        cur ^= 1;
        ALOAD(a2, 2, ncc)                    // used 2 phases into next chunk
    }

    // epilogue: out = acc * sigma + bias.  C/D: col=lane&31, row=(reg&3)+8*(reg>>2)+4*hi
    const float* sigb = sigma + b * 512;
    #pragma unroll
    for (int fm = 0; fm < 2; ++fm) {
        #pragma unroll
        for (int fn = 0; fn < 4; ++fn) {
            #pragma unroll
            for (int reg = 0; reg < 16; ++reg) {
                int row = (reg & 3) + 8 * (reg >> 2) + 4 * hi;
                int o = ob1 * 256 + wv * 64 + fm * 32 + row;
                float v = acc[fm][fn][reg] * sigb[o] + bias[o];
                out[(((size_t)(b * 512 + o) * 64) + y0 + (fn >> 1)) * 64 + (fn & 1) * 32 + l31] = v;
            }
        }
    }
}

extern "C" void kernel_launch(void* const* d_in, const int* in_sizes, int n_in,
                              void* d_out, int out_size, void* d_ws, size_t ws_size,
                              hipStream_t stream) {
    const float* x    = (const float*)d_in[0];
    const float* w    = (const float*)d_in[1];
    const float* wt   = (const float*)d_in[2];
    const float* bias = (const float*)d_in[3];
    const float* aw   = (const float*)d_in[4];
    const float* ab   = (const float*)d_in[5];
    float* out = (float*)d_out;

    // ws layout: style(16KB) | sigma(16KB) | wsq(1MB) | Wf bf16 (4.5MB)
    float* style  = (float*)d_ws;
    float* sigmap = style + 4096;
    float* wsq    = sigmap + 4096;
    ushort* Wf    = (ushort*)(wsq + 512 * 512);

    k_style<<<1024, 256, 0, stream>>>(w, aw, ab, style);
    k_wprep<<<1024, 256, 0, stream>>>(wt, Wf, wsq);
    k_sigma<<<1024, 256, 0, stream>>>(style, wsq, sigmap);
    k_conv <<< 512, 256, 0, stream>>>(x, Wf, style, sigmap, bias, out);
}